// Round 1
// baseline (2257.197 us; speedup 1.0000x reference)
//
#include <hip/hip_runtime.h>
#include <hip/hip_bf16.h>

#define BB 8
#define SS 1024
#define DM 512
#define HH 8
#define DEPTH 64

// ---------------- GEMM: C = A @ W + bias ----------------
// A: 8192 x 512 row-major, W: 512 x 512 row-major, bias: 512
// split==1: C[((b*H+h)*S+s)*64+d]  (head-split)   split==0: C[m*512+n]
__global__ __launch_bounds__(256) void gemm512(const float* __restrict__ A,
    const float* __restrict__ W, const float* __restrict__ bias,
    float* __restrict__ C, int split)
{
    __shared__ float As[16][65];
    __shared__ float Ws[16][65];
    const int tx = threadIdx.x, ty = threadIdx.y;
    const int tid = ty * 16 + tx;
    const int m0 = blockIdx.y * 64, n0 = blockIdx.x * 64;
    float acc[4][4] = {};
    const int lrow = tid >> 2, lk4 = (tid & 3) * 4;   // A-tile loader
    const int wk = tid >> 4, wn4 = (tid & 15) * 4;    // W-tile loader

    for (int k0 = 0; k0 < 512; k0 += 16) {
        __syncthreads();
        float4 a = *(const float4*)(A + (size_t)(m0 + lrow) * 512 + k0 + lk4);
        As[lk4 + 0][lrow] = a.x; As[lk4 + 1][lrow] = a.y;
        As[lk4 + 2][lrow] = a.z; As[lk4 + 3][lrow] = a.w;
        float4 w = *(const float4*)(W + (size_t)(k0 + wk) * 512 + n0 + wn4);
        Ws[wk][wn4 + 0] = w.x; Ws[wk][wn4 + 1] = w.y;
        Ws[wk][wn4 + 2] = w.z; Ws[wk][wn4 + 3] = w.w;
        __syncthreads();
        #pragma unroll
        for (int kk = 0; kk < 16; ++kk) {
            float ra[4], rb[4];
            #pragma unroll
            for (int i = 0; i < 4; ++i) ra[i] = As[kk][ty * 4 + i];
            #pragma unroll
            for (int j = 0; j < 4; ++j) rb[j] = Ws[kk][tx * 4 + j];
            #pragma unroll
            for (int i = 0; i < 4; ++i)
                #pragma unroll
                for (int j = 0; j < 4; ++j) acc[i][j] += ra[i] * rb[j];
        }
    }
    #pragma unroll
    for (int i = 0; i < 4; ++i) {
        int m = m0 + ty * 4 + i;
        #pragma unroll
        for (int j = 0; j < 4; ++j) {
            int n = n0 + tx * 4 + j;
            float v = acc[i][j] + bias[n];
            if (split) {
                int b = m >> 10, s = m & 1023, h = n >> 6, d = n & 63;
                C[((size_t)(b * HH + h) * SS + s) * 64 + d] = v;
            } else {
                C[(size_t)m * 512 + n] = v;
            }
        }
    }
}

// ---------------- Fused attention ----------------
// One block per (b, h, 16 q-rows). 256 threads.
__global__ __launch_bounds__(256) void attn_fused(
    const float* __restrict__ qh, const float* __restrict__ kh,
    const float* __restrict__ vh, const float* __restrict__ mask,
    const float* __restrict__ adj, const float* __restrict__ dist,
    float* __restrict__ attn_out, float* __restrict__ ctx_out)
{
    __shared__ float qs[16][65];
    __shared__ float kvs[128][65];
    __shared__ float srow[16][1025];
    __shared__ float nm[1024];
    __shared__ float red[16][17];
    __shared__ float red2[16][17];
    __shared__ float rowm[16], rowl[16], dmx[16], dls[16];

    const int tid = threadIdx.x;
    const int qt = blockIdx.x, h = blockIdx.y, b = blockIdx.z;
    const int q0 = qt * 16;
    const size_t headbase = ((size_t)(b * HH + h)) * SS * DEPTH;

    // phase 0: load Q-tile and mask row
    {
        int r0 = tid >> 4, c4 = (tid & 15) * 4;
        const float4 qv = *(const float4*)(qh + headbase + (size_t)(q0 + r0) * 64 + c4);
        qs[r0][c4 + 0] = qv.x; qs[r0][c4 + 1] = qv.y;
        qs[r0][c4 + 2] = qv.z; qs[r0][c4 + 3] = qv.w;
        #pragma unroll
        for (int i = 0; i < 4; ++i) {
            int k = tid + 256 * i;
            nm[k] = mask[(size_t)b * SS + k] * -1e9f;
        }
    }

    // phase 1: logits = qh . kh / 8 + nm
    {
        const int qr = tid >> 4, kl = tid & 15;
        for (int c = 0; c < 8; ++c) {
            __syncthreads();
            #pragma unroll
            for (int i = 0; i < 8; ++i) {
                int idx = tid + 256 * i;
                int row = idx >> 4, c4 = (idx & 15) * 4;
                const float4 kv = *(const float4*)(kh + headbase + (size_t)(c * 128 + row) * 64 + c4);
                kvs[row][c4 + 0] = kv.x; kvs[row][c4 + 1] = kv.y;
                kvs[row][c4 + 2] = kv.z; kvs[row][c4 + 3] = kv.w;
            }
            __syncthreads();
            float acc[8] = {};
            for (int d = 0; d < 64; ++d) {
                float qv = qs[qr][d];
                #pragma unroll
                for (int u = 0; u < 8; ++u) acc[u] += qv * kvs[kl + 16 * u][d];
            }
            #pragma unroll
            for (int u = 0; u < 8; ++u) {
                int k = c * 128 + kl + 16 * u;
                srow[qr][k] = acc[u] * 0.125f + nm[k];
            }
        }
    }
    __syncthreads();

    // phase 2: softmax over each of 16 rows (16 threads per row)
    const int r = tid >> 4, c16 = tid & 15;
    {
        float pm = -3.0e38f;
        for (int i = 0; i < 64; ++i) pm = fmaxf(pm, srow[r][c16 + 16 * i]);
        red[r][c16] = pm;
        __syncthreads();
        if (c16 == 0) {
            float m = red[r][0];
            for (int j = 1; j < 16; ++j) m = fmaxf(m, red[r][j]);
            rowm[r] = m;
        }
        __syncthreads();
        float m = rowm[r];
        float ps = 0.f;
        for (int i = 0; i < 64; ++i) {
            int k = c16 + 16 * i;
            float e = expf(srow[r][k] - m);
            srow[r][k] = e;
            ps += e;
        }
        red[r][c16] = ps;
        __syncthreads();
        if (c16 == 0) {
            float ssum = 0.f;
            for (int j = 0; j < 16; ++j) ssum += red[r][j];
            rowl[r] = ssum;
        }
        __syncthreads();
    }

    // phase 2b: dist softmax (online, per q-row)
    {
        const float* drow = dist + ((size_t)(b * SS + q0 + r)) * SS;
        float dm_t = -3.0e38f, dl_t = 0.f;
        for (int i = 0; i < 64; ++i) {
            int k = c16 + 16 * i;
            float x = drow[k] + nm[k];
            if (x > dm_t) { dl_t = dl_t * expf(dm_t - x) + 1.f; dm_t = x; }
            else dl_t += expf(x - dm_t);
        }
        red[r][c16] = dm_t; red2[r][c16] = dl_t;
        __syncthreads();
        if (c16 == 0) {
            float M = red[r][0];
            for (int j = 1; j < 16; ++j) M = fmaxf(M, red[r][j]);
            float L = 0.f;
            for (int j = 0; j < 16; ++j) L += red2[r][j] * expf(red[r][j] - M);
            dmx[r] = M; dls[r] = L;
        }
    }
    __syncthreads();

    // phase 3: attn = P/l * adj * dist_sm ; write attn out and back to srow
    for (int q = 0; q < 16; ++q) {
        const int qg = q0 + q;
        const float invP = 1.0f / rowl[q];
        const float Md = dmx[q];
        const float invL = 1.0f / dls[q];
        const size_t rbase = ((size_t)(b * SS + qg)) * SS;
        float* aout = attn_out + (((size_t)(b * HH + h)) * SS + qg) * SS;
        for (int k = tid; k < 1024; k += 256) {
            float ds = expf(dist[rbase + k] + nm[k] - Md) * invL;
            float val = srow[q][k] * invP * adj[rbase + k] * ds;
            aout[k] = val;
            srow[q][k] = val;
        }
    }

    // phase 4: ctx = attn @ vh, write in concat layout
    {
        const int qr = tid >> 4, d4 = (tid & 15) * 4;
        float acc[4] = {};
        for (int c = 0; c < 8; ++c) {
            __syncthreads();
            #pragma unroll
            for (int i = 0; i < 8; ++i) {
                int idx = tid + 256 * i;
                int row = idx >> 4, c4 = (idx & 15) * 4;
                const float4 vv = *(const float4*)(vh + headbase + (size_t)(c * 128 + row) * 64 + c4);
                kvs[row][c4 + 0] = vv.x; kvs[row][c4 + 1] = vv.y;
                kvs[row][c4 + 2] = vv.z; kvs[row][c4 + 3] = vv.w;
            }
            __syncthreads();
            for (int kk = 0; kk < 128; ++kk) {
                float p = srow[qr][c * 128 + kk];
                #pragma unroll
                for (int j = 0; j < 4; ++j) acc[j] += p * kvs[kk][d4 + j];
            }
        }
        float* cp = ctx_out + ((size_t)(b * SS + q0 + qr)) * DM + h * 64 + d4;
        float4 o; o.x = acc[0]; o.y = acc[1]; o.z = acc[2]; o.w = acc[3];
        *(float4*)cp = o;
    }
}

extern "C" void kernel_launch(void* const* d_in, const int* in_sizes, int n_in,
                              void* d_out, int out_size, void* d_ws, size_t ws_size,
                              hipStream_t stream) {
    const float* q    = (const float*)d_in[0];
    const float* k    = (const float*)d_in[1];
    const float* v    = (const float*)d_in[2];
    const float* mask = (const float*)d_in[3];
    const float* adj  = (const float*)d_in[4];
    const float* dist = (const float*)d_in[5];
    const float* Wq   = (const float*)d_in[6];
    const float* bq   = (const float*)d_in[7];
    const float* Wk   = (const float*)d_in[8];
    const float* bk   = (const float*)d_in[9];
    const float* Wv   = (const float*)d_in[10];
    const float* bv   = (const float*)d_in[11];
    const float* Wo   = (const float*)d_in[12];
    const float* bo   = (const float*)d_in[13];

    const size_t NTOK = (size_t)BB * SS * DM; // 4,194,304
    float* ws   = (float*)d_ws;
    float* qh   = ws;
    float* kh   = ws + NTOK;
    float* vh   = ws + 2 * NTOK;
    float* ctxc = ws + 3 * NTOK;

    float* outp = (float*)d_out;
    float* attn = outp + NTOK; // out first, then attn

    dim3 gb(8, 128);      // N/64, M/64
    dim3 tb(16, 16);
    gemm512<<<gb, tb, 0, stream>>>(q, Wq, bq, qh, 1);
    gemm512<<<gb, tb, 0, stream>>>(k, Wk, bk, kh, 1);
    gemm512<<<gb, tb, 0, stream>>>(v, Wv, bv, vh, 1);

    attn_fused<<<dim3(64, 8, 8), 256, 0, stream>>>(qh, kh, vh, mask, adj, dist, attn, ctxc);

    gemm512<<<gb, tb, 0, stream>>>(ctxc, Wo, bo, outp, 0);
}

// Round 2
// 676.095 us; speedup vs baseline: 3.3386x; 3.3386x over previous
//
#include <hip/hip_runtime.h>
#include <hip/hip_bf16.h>

#define BB 8
#define SS 1024
#define DM 512
#define HH 8

typedef __bf16 bf16x8 __attribute__((ext_vector_type(8)));
typedef float f32x4 __attribute__((ext_vector_type(4)));

__device__ __forceinline__ f32x4 mfma16(bf16x8 a, bf16x8 b, f32x4 c) {
    return __builtin_amdgcn_mfma_f32_16x16x32_bf16(a, b, c, 0, 0, 0);
}

// XOR swizzle: slot = (row&7) ^ ((row&8)>>2), applied to byte bits [4..6]
__device__ __forceinline__ int swzoff(int row, int off) {
    return off ^ ((((row) & 7) ^ (((row) & 8) >> 2)) << 4);
}

// ---------------- GEMM: C = A @ W + bias ----------------
// mode 0: fp32 C[m*512+n]
// mode 1: bf16 hi/lo head-split  Chi/Clo[((b*8+h)*1024+s)*64+d]
// mode 2: bf16 transposed        Chi[((b*8+h)*64+d)*1024+s]
__global__ __launch_bounds__(256) void gemm512(const float* __restrict__ A,
    const float* __restrict__ W, const float* __restrict__ bias,
    float* __restrict__ Cf, __bf16* __restrict__ Chi, __bf16* __restrict__ Clo,
    int mode)
{
    __shared__ float As[16][65];
    __shared__ float Ws[16][65];
    const int tx = threadIdx.x, ty = threadIdx.y;
    const int tid = ty * 16 + tx;
    const int m0 = blockIdx.y * 64, n0 = blockIdx.x * 64;
    float acc[4][4] = {};
    const int lrow = tid >> 2, lk4 = (tid & 3) * 4;
    const int wk = tid >> 4, wn4 = (tid & 15) * 4;

    for (int k0 = 0; k0 < 512; k0 += 16) {
        __syncthreads();
        float4 a = *(const float4*)(A + (size_t)(m0 + lrow) * 512 + k0 + lk4);
        As[lk4 + 0][lrow] = a.x; As[lk4 + 1][lrow] = a.y;
        As[lk4 + 2][lrow] = a.z; As[lk4 + 3][lrow] = a.w;
        float4 w = *(const float4*)(W + (size_t)(k0 + wk) * 512 + n0 + wn4);
        Ws[wk][wn4 + 0] = w.x; Ws[wk][wn4 + 1] = w.y;
        Ws[wk][wn4 + 2] = w.z; Ws[wk][wn4 + 3] = w.w;
        __syncthreads();
        #pragma unroll
        for (int kk = 0; kk < 16; ++kk) {
            float ra[4], rb[4];
            #pragma unroll
            for (int i = 0; i < 4; ++i) ra[i] = As[kk][ty * 4 + i];
            #pragma unroll
            for (int j = 0; j < 4; ++j) rb[j] = Ws[kk][tx * 4 + j];
            #pragma unroll
            for (int i = 0; i < 4; ++i)
                #pragma unroll
                for (int j = 0; j < 4; ++j) acc[i][j] += ra[i] * rb[j];
        }
    }
    #pragma unroll
    for (int i = 0; i < 4; ++i) {
        int m = m0 + ty * 4 + i;
        #pragma unroll
        for (int j = 0; j < 4; ++j) {
            int n = n0 + tx * 4 + j;
            float v = acc[i][j] + bias[n];
            if (mode == 0) {
                Cf[(size_t)m * 512 + n] = v;
            } else {
                int b = m >> 10, s = m & 1023, h = n >> 6, d = n & 63;
                if (mode == 1) {
                    size_t idx = ((size_t)(b * HH + h) * SS + s) * 64 + d;
                    __bf16 hv = (__bf16)v;
                    Chi[idx] = hv;
                    Clo[idx] = (__bf16)(v - (float)hv);
                } else {
                    size_t idx = ((size_t)(b * HH + h) * 64 + d) * SS + s;
                    Chi[idx] = (__bf16)v;
                }
            }
        }
    }
}

// ---------------- Fused attention (MFMA) ----------------
// grid (64 qtiles, 8 b), 256 threads = 4 waves. Each block: 16 q-rows, loops 8 heads.
__global__ __launch_bounds__(256) void attn_mfma(
    const __bf16* __restrict__ qhi, const __bf16* __restrict__ qlo,
    const __bf16* __restrict__ khi, const __bf16* __restrict__ klo,
    const __bf16* __restrict__ vt,
    const float* __restrict__ mask, const float* __restrict__ adj,
    const float* __restrict__ dist,
    float* __restrict__ attn_out, float* __restrict__ ctxc)
{
    __shared__ __align__(16) unsigned short Pl[16 * 1024]; // P bf16 (swizzled)
    __shared__ __align__(16) unsigned short Gl[16 * 1024]; // adj*exp(dist+nm-Md) bf16 (swizzled)
    __shared__ float nmS[1024];
    __shared__ float redm[4][16];
    __shared__ float reds[4][16];
    __shared__ float rowIL[16];

    const int tid = threadIdx.x;
    const int w = tid >> 6;
    const int lane = tid & 63;
    const int l15 = lane & 15;
    const int lg = lane >> 4;
    const int qt = blockIdx.x, b = blockIdx.y;
    const int q0 = qt * 16;

    // mask row -> LDS
    #pragma unroll
    for (int i = 0; i < 4; ++i) {
        int c = tid + 256 * i;
        nmS[c] = mask[(size_t)b * SS + c] * -1e9f;
    }
    __syncthreads();

    // ---- head-independent: dist softmax stats + G = adj * exp(dist+nm-Md) ----
    {
        const int grow = w * 4 + lg;                       // one row per 16-lane group
        const size_t drow = ((size_t)b * SS + q0 + grow) * SS;
        float mx = -3.0e38f;
        #pragma unroll
        for (int i = 0; i < 64; ++i) {
            int c = l15 + 16 * i;
            mx = fmaxf(mx, dist[drow + c] + nmS[c]);
        }
        #pragma unroll
        for (int off = 1; off < 16; off <<= 1)
            mx = fmaxf(mx, __shfl_xor(mx, off, 64));
        float sm = 0.f;
        #pragma unroll
        for (int i = 0; i < 64; ++i) {
            int c = l15 + 16 * i;
            float x = dist[drow + c] + nmS[c];
            float e = expf(x - mx);
            sm += e;
            float gv = adj[drow + c] * e;
            *(__bf16*)((char*)Gl + swzoff(grow, grow * 2048 + c * 2)) = (__bf16)gv;
        }
        #pragma unroll
        for (int off = 1; off < 16; off <<= 1)
            sm += __shfl_xor(sm, off, 64);
        if (l15 == 0) rowIL[grow] = 1.0f / sm;
    }
    __syncthreads();

    float invLd[4], nmv[16];
    #pragma unroll
    for (int r = 0; r < 4; ++r) invLd[r] = rowIL[lg * 4 + r];
    #pragma unroll
    for (int nt = 0; nt < 16; ++nt) nmv[nt] = nmS[256 * w + 16 * nt + l15];

    for (int h = 0; h < HH; ++h) {
        const size_t hb = ((size_t)(b * HH + h)) * SS * 64;

        // Q fragments (A: row = l15, k = lg*8 + j + 32*ks)
        bf16x8 qfh[2], qfl[2];
        #pragma unroll
        for (int ks = 0; ks < 2; ++ks) {
            size_t off = hb + (size_t)(q0 + l15) * 64 + ks * 32 + lg * 8;
            qfh[ks] = *(const bf16x8*)(qhi + off);
            qfl[ks] = *(const bf16x8*)(qlo + off);
        }

        // QK^T: wave w covers keys [256w, 256w+256), 16 n-tiles
        f32x4 sv[16];
        #pragma unroll
        for (int nt = 0; nt < 16; ++nt) {
            f32x4 acc = {0.f, 0.f, 0.f, 0.f};
            int key = 256 * w + 16 * nt + l15;
            #pragma unroll
            for (int ks = 0; ks < 2; ++ks) {
                size_t off = hb + (size_t)key * 64 + ks * 32 + lg * 8;
                bf16x8 kf = *(const bf16x8*)(khi + off);
                bf16x8 kl = *(const bf16x8*)(klo + off);
                acc = mfma16(qfh[ks], kf, acc);
                acc = mfma16(qfl[ks], kf, acc);
                acc = mfma16(qfh[ks], kl, acc);
            }
            #pragma unroll
            for (int r = 0; r < 4; ++r)
                acc[r] = acc[r] * 0.125f + nmv[nt];
            sv[nt] = acc;
        }

        // row max (rows R = lg*4+r within wave, cross-wave via LDS)
        float m4[4];
        #pragma unroll
        for (int r = 0; r < 4; ++r) {
            float m = sv[0][r];
            #pragma unroll
            for (int nt = 1; nt < 16; ++nt) m = fmaxf(m, sv[nt][r]);
            #pragma unroll
            for (int off = 1; off < 16; off <<= 1)
                m = fmaxf(m, __shfl_xor(m, off, 64));
            m4[r] = m;
        }
        if (l15 == 0) {
            #pragma unroll
            for (int r = 0; r < 4; ++r) redm[w][lg * 4 + r] = m4[r];
        }
        __syncthreads();
        float l4[4];
        #pragma unroll
        for (int r = 0; r < 4; ++r) {
            int R = lg * 4 + r;
            m4[r] = fmaxf(fmaxf(redm[0][R], redm[1][R]), fmaxf(redm[2][R], redm[3][R]));
            l4[r] = 0.f;
        }
        #pragma unroll
        for (int nt = 0; nt < 16; ++nt) {
            #pragma unroll
            for (int r = 0; r < 4; ++r) {
                float p = expf(sv[nt][r] - m4[r]);
                sv[nt][r] = p;
                l4[r] += p;
            }
        }
        #pragma unroll
        for (int r = 0; r < 4; ++r) {
            #pragma unroll
            for (int off = 1; off < 16; off <<= 1)
                l4[r] += __shfl_xor(l4[r], off, 64);
        }
        if (l15 == 0) {
            #pragma unroll
            for (int r = 0; r < 4; ++r) reds[w][lg * 4 + r] = l4[r];
        }
        __syncthreads();
        float invls[4];
        #pragma unroll
        for (int r = 0; r < 4; ++r) {
            int R = lg * 4 + r;
            invls[r] = 1.0f / (reds[0][R] + reds[1][R] + reds[2][R] + reds[3][R]);
        }

        // apply gates, write attn, store P (bf16, swizzled)
        float* aout = attn_out + ((size_t)(b * HH + h)) * SS * SS;
        #pragma unroll
        for (int nt = 0; nt < 16; ++nt) {
            int key = 256 * w + 16 * nt + l15;
            #pragma unroll
            for (int r = 0; r < 4; ++r) {
                int R = lg * 4 + r;
                float gv = (float)(*(const __bf16*)((const char*)Gl + swzoff(R, R * 2048 + key * 2)));
                float av = sv[nt][r] * invls[r] * gv * invLd[r];
                aout[(size_t)(q0 + R) * SS + key] = av;
                *(__bf16*)((char*)Pl + swzoff(R, R * 2048 + key * 2)) = (__bf16)av;
            }
        }
        __syncthreads();

        // PV: wave w owns d-cols [16w,16w+16); A = P (LDS), B = vt rows (global, contiguous 16B)
        f32x4 c0 = {0.f, 0.f, 0.f, 0.f};
        const __bf16* vb = vt + ((size_t)(b * HH + h) * 64 + 16 * w + l15) * SS + lg * 8;
        #pragma unroll
        for (int ks = 0; ks < 32; ++ks) {
            int k0 = ks * 32 + lg * 8;
            bf16x8 pa = *(const bf16x8*)((const char*)Pl + swzoff(l15, l15 * 2048 + k0 * 2));
            bf16x8 vf = *(const bf16x8*)(vb + ks * 32);
            c0 = mfma16(pa, vf, c0);
        }
        #pragma unroll
        for (int r = 0; r < 4; ++r) {
            ctxc[((size_t)b * SS + q0 + lg * 4 + r) * DM + h * 64 + 16 * w + l15] = c0[r];
        }
        __syncthreads();
    }
}

extern "C" void kernel_launch(void* const* d_in, const int* in_sizes, int n_in,
                              void* d_out, int out_size, void* d_ws, size_t ws_size,
                              hipStream_t stream) {
    const float* q    = (const float*)d_in[0];
    const float* k    = (const float*)d_in[1];
    const float* v    = (const float*)d_in[2];
    const float* mask = (const float*)d_in[3];
    const float* adj  = (const float*)d_in[4];
    const float* dist = (const float*)d_in[5];
    const float* Wq   = (const float*)d_in[6];
    const float* bq   = (const float*)d_in[7];
    const float* Wk   = (const float*)d_in[8];
    const float* bk   = (const float*)d_in[9];
    const float* Wv   = (const float*)d_in[10];
    const float* bv   = (const float*)d_in[11];
    const float* Wo   = (const float*)d_in[12];
    const float* bo   = (const float*)d_in[13];

    const size_t NT = (size_t)BB * SS * DM; // 4,194,304
    __bf16* qhi = (__bf16*)d_ws;
    __bf16* qlo = qhi + NT;
    __bf16* khi = qlo + NT;
    __bf16* klo = khi + NT;
    __bf16* vt  = klo + NT;
    float* ctxc = (float*)(vt + NT);

    float* outp = (float*)d_out;
    float* attn = outp + NT;

    dim3 gb(8, 128);
    dim3 tb(16, 16);
    gemm512<<<gb, tb, 0, stream>>>(q, Wq, bq, nullptr, qhi, qlo, 1);
    gemm512<<<gb, tb, 0, stream>>>(k, Wk, bk, nullptr, khi, klo, 1);
    gemm512<<<gb, tb, 0, stream>>>(v, Wv, bv, nullptr, vt, nullptr, 2);

    attn_mfma<<<dim3(64, 8), 256, 0, stream>>>(qhi, qlo, khi, klo, vt, mask, adj, dist, attn, ctxc);

    gemm512<<<gb, tb, 0, stream>>>(ctxc, Wo, bo, outp, nullptr, nullptr, 0);
}

// Round 3
// 660.456 us; speedup vs baseline: 3.4176x; 1.0237x over previous
//
#include <hip/hip_runtime.h>
#include <hip/hip_bf16.h>

#define BB 8
#define SS 1024
#define DM 512
#define HH 8

typedef __bf16 bf16x8 __attribute__((ext_vector_type(8)));
typedef __bf16 bf16x4 __attribute__((ext_vector_type(4)));
typedef float f32x4 __attribute__((ext_vector_type(4)));

__device__ __forceinline__ f32x4 mfma16(bf16x8 a, bf16x8 b, f32x4 c) {
    return __builtin_amdgcn_mfma_f32_16x16x32_bf16(a, b, c, 0, 0, 0);
}

// ---------------- GEMM: C = A @ W + bias ----------------
// mode 0: fp32 C[m*512+n]
// mode 1: bf16 hi/lo head-split  Chi/Clo[((b*8+h)*1024+s)*64+d]
// mode 2: bf16 transposed        Chi[((b*8+h)*64+d)*1024+s]
__global__ __launch_bounds__(256) void gemm512(const float* __restrict__ A,
    const float* __restrict__ W, const float* __restrict__ bias,
    float* __restrict__ Cf, __bf16* __restrict__ Chi, __bf16* __restrict__ Clo,
    int mode)
{
    __shared__ float As[16][65];
    __shared__ float Ws[16][65];
    const int tx = threadIdx.x, ty = threadIdx.y;
    const int tid = ty * 16 + tx;
    const int m0 = blockIdx.y * 64, n0 = blockIdx.x * 64;
    float acc[4][4] = {};
    const int lrow = tid >> 2, lk4 = (tid & 3) * 4;
    const int wk = tid >> 4, wn4 = (tid & 15) * 4;

    for (int k0 = 0; k0 < 512; k0 += 16) {
        __syncthreads();
        float4 a = *(const float4*)(A + (size_t)(m0 + lrow) * 512 + k0 + lk4);
        As[lk4 + 0][lrow] = a.x; As[lk4 + 1][lrow] = a.y;
        As[lk4 + 2][lrow] = a.z; As[lk4 + 3][lrow] = a.w;
        float4 w = *(const float4*)(W + (size_t)(k0 + wk) * 512 + n0 + wn4);
        Ws[wk][wn4 + 0] = w.x; Ws[wk][wn4 + 1] = w.y;
        Ws[wk][wn4 + 2] = w.z; Ws[wk][wn4 + 3] = w.w;
        __syncthreads();
        #pragma unroll
        for (int kk = 0; kk < 16; ++kk) {
            float ra[4], rb[4];
            #pragma unroll
            for (int i = 0; i < 4; ++i) ra[i] = As[kk][ty * 4 + i];
            #pragma unroll
            for (int j = 0; j < 4; ++j) rb[j] = Ws[kk][tx * 4 + j];
            #pragma unroll
            for (int i = 0; i < 4; ++i)
                #pragma unroll
                for (int j = 0; j < 4; ++j) acc[i][j] += ra[i] * rb[j];
        }
    }
    #pragma unroll
    for (int i = 0; i < 4; ++i) {
        int m = m0 + ty * 4 + i;
        #pragma unroll
        for (int j = 0; j < 4; ++j) {
            int n = n0 + tx * 4 + j;
            float v = acc[i][j] + bias[n];
            if (mode == 0) {
                Cf[(size_t)m * 512 + n] = v;
            } else {
                int b = m >> 10, s = m & 1023, h = n >> 6, d = n & 63;
                if (mode == 1) {
                    size_t idx = ((size_t)(b * HH + h) * SS + s) * 64 + d;
                    __bf16 hv = (__bf16)v;
                    Chi[idx] = hv;
                    Clo[idx] = (__bf16)(v - (float)hv);
                } else {
                    size_t idx = ((size_t)(b * HH + h) * 64 + d) * SS + s;
                    Chi[idx] = (__bf16)v;
                }
            }
        }
    }
}

// ---------------- Fused attention (MFMA, wave-per-head) ----------------
// grid (64 qtiles, 8 b), 512 threads = 8 waves. Wave w handles head w for the
// block's 16 q-rows. No barriers after setup.
__global__ __launch_bounds__(512, 4) void attn_mfma(
    const __bf16* __restrict__ qhi, const __bf16* __restrict__ qlo,
    const __bf16* __restrict__ khi, const __bf16* __restrict__ klo,
    const __bf16* __restrict__ vt,
    const float* __restrict__ mask, const float* __restrict__ adj,
    const float* __restrict__ dist,
    float* __restrict__ attn_out, float* __restrict__ ctxc)
{
    __shared__ float nmS[1024];
    __shared__ __align__(16) __bf16 G[16][1028];       // adj*exp(dist+nm-Md), bf16
    __shared__ __align__(16) __bf16 Pch[8][16][40];    // per-wave P chunk bounce
    __shared__ float rowIL[16];

    const int tid = threadIdx.x;
    const int w = tid >> 6;          // wave = head
    const int lane = tid & 63;
    const int l15 = lane & 15;
    const int lg = lane >> 4;
    const int q0 = blockIdx.x * 16;
    const int b = blockIdx.y;

    #pragma unroll
    for (int i = 0; i < 2; ++i) {
        int c = tid + 512 * i;
        nmS[c] = mask[(size_t)b * SS + c] * -1e9f;
    }
    __syncthreads();

    // ---- head-independent gate: G = adj * exp(dist + nm - Md), rowIL = 1/Ld ----
    {
        const int row = 2 * w + (lg >> 1);           // each half-wave: one row
        const int kb = (lg & 1) * 512;               // each group: half the keys
        const size_t drow = ((size_t)b * SS + q0 + row) * SS;
        float mx = -3.0e38f;
        #pragma unroll
        for (int j = 0; j < 8; ++j) {
            int c = kb + l15 * 4 + j * 64;
            f32x4 d4 = *(const f32x4*)(dist + drow + c);
            f32x4 n4 = *(const f32x4*)&nmS[c];
            d4 = d4 + n4;
            mx = fmaxf(mx, fmaxf(fmaxf(d4[0], d4[1]), fmaxf(d4[2], d4[3])));
        }
        #pragma unroll
        for (int off = 1; off <= 16; off <<= 1)
            mx = fmaxf(mx, __shfl_xor(mx, off, 64));
        float sm = 0.f;
        #pragma unroll
        for (int j = 0; j < 8; ++j) {
            int c = kb + l15 * 4 + j * 64;
            f32x4 d4 = *(const f32x4*)(dist + drow + c);
            f32x4 n4 = *(const f32x4*)&nmS[c];
            f32x4 a4 = *(const f32x4*)(adj + drow + c);
            bf16x4 g4;
            #pragma unroll
            for (int r = 0; r < 4; ++r) {
                float e = __expf(d4[r] + n4[r] - mx);
                sm += e;
                g4[r] = (__bf16)(a4[r] * e);
            }
            *(bf16x4*)&G[row][c] = g4;
        }
        #pragma unroll
        for (int off = 1; off <= 16; off <<= 1)
            sm += __shfl_xor(sm, off, 64);
        if ((lane & 31) == 0) rowIL[row] = 1.0f / sm;
    }
    __syncthreads();

    // ---- per-wave: this wave's head ----
    const size_t hb = ((size_t)(b * HH + w)) * SS * 64;
    bf16x8 qfh[2], qfl[2];
    #pragma unroll
    for (int ks = 0; ks < 2; ++ks) {
        size_t off = hb + (size_t)(q0 + l15) * 64 + ks * 32 + lg * 8;
        qfh[ks] = *(const bf16x8*)(qhi + off);
        qfl[ks] = *(const bf16x8*)(qlo + off);
    }

    // pass 1: online row max m and denom l. C layout: row=key(lg*4+r), col=q(l15)
    float m = -3.0e38f, l = 0.f;
    for (int nt = 0; nt < 64; ++nt) {
        f32x4 acc = {0.f, 0.f, 0.f, 0.f};
        #pragma unroll
        for (int ks = 0; ks < 2; ++ks) {
            size_t off = hb + (size_t)(nt * 16 + l15) * 64 + ks * 32 + lg * 8;
            bf16x8 kh8 = *(const bf16x8*)(khi + off);
            bf16x8 kl8 = *(const bf16x8*)(klo + off);
            acc = mfma16(kh8, qfh[ks], acc);
            acc = mfma16(kh8, qfl[ks], acc);
            acc = mfma16(kl8, qfh[ks], acc);
        }
        f32x4 nm4 = *(const f32x4*)&nmS[nt * 16 + lg * 4];
        f32x4 s = acc * 0.125f + nm4;
        float mt = fmaxf(fmaxf(s[0], s[1]), fmaxf(s[2], s[3]));
        float mn = fmaxf(m, mt);
        l = l * __expf(m - mn) + __expf(s[0] - mn) + __expf(s[1] - mn)
            + __expf(s[2] - mn) + __expf(s[3] - mn);
        m = mn;
    }
    // combine partials across the 4 lane-groups (same q-row at lanes ^16, ^32)
    #pragma unroll
    for (int off = 16; off <= 32; off <<= 1) {
        float mo = __shfl_xor(m, off, 64);
        float lo_ = __shfl_xor(l, off, 64);
        float mn = fmaxf(m, mo);
        l = l * __expf(m - mn) + lo_ * __expf(mo - mn);
        m = mn;
    }
    const float coef = (1.0f / l) * rowIL[l15];

    // pass 2: recompute S, gate, write attn, PV
    f32x4 cacc[4];
    #pragma unroll
    for (int dt = 0; dt < 4; ++dt) cacc[dt] = (f32x4){0.f, 0.f, 0.f, 0.f};
    float* aout = attn_out + ((size_t)(b * HH + w)) * SS * SS;

    for (int c = 0; c < 32; ++c) {
        #pragma unroll
        for (int t = 0; t < 2; ++t) {
            int nt = c * 2 + t;
            f32x4 acc = {0.f, 0.f, 0.f, 0.f};
            #pragma unroll
            for (int ks = 0; ks < 2; ++ks) {
                size_t off = hb + (size_t)(nt * 16 + l15) * 64 + ks * 32 + lg * 8;
                bf16x8 kh8 = *(const bf16x8*)(khi + off);
                bf16x8 kl8 = *(const bf16x8*)(klo + off);
                acc = mfma16(kh8, qfh[ks], acc);
                acc = mfma16(kh8, qfl[ks], acc);
                acc = mfma16(kl8, qfh[ks], acc);
            }
            f32x4 nm4 = *(const f32x4*)&nmS[nt * 16 + lg * 4];
            bf16x4 g4 = *(const bf16x4*)&G[l15][nt * 16 + lg * 4];
            f32x4 av;
            bf16x4 pb;
            #pragma unroll
            for (int r = 0; r < 4; ++r) {
                float s = acc[r] * 0.125f + nm4[r];
                float p = __expf(s - m) * coef * (float)g4[r];
                av[r] = p;
                pb[r] = (__bf16)p;
            }
            __builtin_nontemporal_store(av,
                (f32x4*)(aout + (size_t)(q0 + l15) * SS + nt * 16 + lg * 4));
            *(bf16x4*)&Pch[w][l15][t * 16 + lg * 4] = pb;
        }
        bf16x8 pa = *(const bf16x8*)&Pch[w][l15][lg * 8];
        #pragma unroll
        for (int dt = 0; dt < 4; ++dt) {
            const __bf16* vb = vt + ((size_t)(b * HH + w) * 64 + dt * 16 + l15) * SS
                               + c * 32 + lg * 8;
            cacc[dt] = mfma16(pa, *(const bf16x8*)vb, cacc[dt]);
        }
    }

    #pragma unroll
    for (int dt = 0; dt < 4; ++dt)
        #pragma unroll
        for (int r = 0; r < 4; ++r)
            ctxc[((size_t)b * SS + q0 + lg * 4 + r) * DM + w * 64 + dt * 16 + l15]
                = cacc[dt][r];
}

extern "C" void kernel_launch(void* const* d_in, const int* in_sizes, int n_in,
                              void* d_out, int out_size, void* d_ws, size_t ws_size,
                              hipStream_t stream) {
    const float* q    = (const float*)d_in[0];
    const float* k    = (const float*)d_in[1];
    const float* v    = (const float*)d_in[2];
    const float* mask = (const float*)d_in[3];
    const float* adj  = (const float*)d_in[4];
    const float* dist = (const float*)d_in[5];
    const float* Wq   = (const float*)d_in[6];
    const float* bq   = (const float*)d_in[7];
    const float* Wk   = (const float*)d_in[8];
    const float* bk   = (const float*)d_in[9];
    const float* Wv   = (const float*)d_in[10];
    const float* bv   = (const float*)d_in[11];
    const float* Wo   = (const float*)d_in[12];
    const float* bo   = (const float*)d_in[13];

    const size_t NT = (size_t)BB * SS * DM; // 4,194,304
    __bf16* qhi = (__bf16*)d_ws;
    __bf16* qlo = qhi + NT;
    __bf16* khi = qlo + NT;
    __bf16* klo = khi + NT;
    __bf16* vt  = klo + NT;
    float* ctxc = (float*)(vt + NT);

    float* outp = (float*)d_out;
    float* attn = outp + NT;

    dim3 gb(8, 128);
    dim3 tb(16, 16);
    gemm512<<<gb, tb, 0, stream>>>(q, Wq, bq, nullptr, qhi, qlo, 1);
    gemm512<<<gb, tb, 0, stream>>>(k, Wk, bk, nullptr, khi, klo, 1);
    gemm512<<<gb, tb, 0, stream>>>(v, Wv, bv, nullptr, vt, nullptr, 2);

    attn_mfma<<<dim3(64, 8), 512, 0, stream>>>(qhi, qlo, khi, klo, vt, mask, adj, dist, attn, ctxc);

    gemm512<<<gb, tb, 0, stream>>>(ctxc, Wo, bo, outp, nullptr, nullptr, 0);
}

// Round 4
// 490.987 us; speedup vs baseline: 4.5973x; 1.3452x over previous
//
#include <hip/hip_runtime.h>
#include <hip/hip_bf16.h>

#define BB 8
#define SS 1024
#define DM 512
#define HH 8

typedef __bf16 bf16x8 __attribute__((ext_vector_type(8)));
typedef __bf16 bf16x4 __attribute__((ext_vector_type(4)));
typedef float f32x4 __attribute__((ext_vector_type(4)));

__device__ __forceinline__ f32x4 mfma16(bf16x8 a, bf16x8 b, f32x4 c) {
    return __builtin_amdgcn_mfma_f32_16x16x32_bf16(a, b, c, 0, 0, 0);
}

// ---------------- W transpose + hi/lo split ----------------
// Wt[n][k] = W[k][n], bf16 hi + lo. grid (8,8,4), 256 thr.
__global__ __launch_bounds__(256) void wconv(
    const float* __restrict__ W0, const float* __restrict__ W1,
    const float* __restrict__ W2, const float* __restrict__ W3,
    __bf16* __restrict__ th, __bf16* __restrict__ tl)
{
    const float* W = blockIdx.z == 0 ? W0 : blockIdx.z == 1 ? W1
                   : blockIdx.z == 2 ? W2 : W3;
    __bf16* oh = th + (size_t)blockIdx.z * 512 * 512;
    __bf16* ol = tl + (size_t)blockIdx.z * 512 * 512;
    __shared__ float T[64][65];
    const int k0 = blockIdx.x * 64, n0 = blockIdx.y * 64;
    const int r = threadIdx.x >> 4, c4 = (threadIdx.x & 15) * 4;
    #pragma unroll
    for (int p = 0; p < 4; ++p) {
        float4 v = *(const float4*)(W + (size_t)(k0 + p * 16 + r) * 512 + n0 + c4);
        T[p * 16 + r][c4 + 0] = v.x; T[p * 16 + r][c4 + 1] = v.y;
        T[p * 16 + r][c4 + 2] = v.z; T[p * 16 + r][c4 + 3] = v.w;
    }
    __syncthreads();
    #pragma unroll
    for (int p = 0; p < 4; ++p) {
        int n = n0 + p * 16 + r;
        bf16x4 h4, l4;
        #pragma unroll
        for (int j = 0; j < 4; ++j) {
            float x = T[c4 + j][p * 16 + r];
            __bf16 h = (__bf16)x;
            h4[j] = h; l4[j] = (__bf16)(x - (float)h);
        }
        *(bf16x4*)(oh + (size_t)n * 512 + k0 + c4) = h4;
        *(bf16x4*)(ol + (size_t)n * 512 + k0 + c4) = l4;
    }
}

// ---------------- MFMA GEMM: C = A @ W + bias ----------------
// AM=0: A fp32 (convert to hi/lo in-reg). AM=1: A = Ahi/Alo bf16.
// OM=0: fp32 C[m][512]. OM=1: bf16 head-split. OM=2: bf16 transposed [b,h,d,s].
// grid (8 n-blk, 128 m-blk), 256 thr = 4 waves; wave: 16 rows x 64 cols.
template<int AM, int OM>
__global__ __launch_bounds__(256, 4) void gemm_mfma(
    const float* __restrict__ Af,
    const __bf16* __restrict__ Ahi, const __bf16* __restrict__ Alo,
    const __bf16* __restrict__ Wth, const __bf16* __restrict__ Wtl,
    const float* __restrict__ bias,
    float* __restrict__ Cf, __bf16* __restrict__ Cb)
{
    const int tid = threadIdx.x;
    const int w = tid >> 6, lane = tid & 63, l15 = lane & 15, lg = lane >> 4;
    const int n0 = blockIdx.x * 64, m0 = blockIdx.y * 64;
    const int mrow = m0 + w * 16 + l15;
    f32x4 acc[4] = {};
    const __bf16* wp = Wth + (size_t)(n0 + l15) * 512 + lg * 8;
    const __bf16* wl = Wtl + (size_t)(n0 + l15) * 512 + lg * 8;

    #pragma unroll 2
    for (int k0 = 0; k0 < 512; k0 += 32) {
        bf16x8 ah, al;
        if (AM == 0) {
            const float* ap = Af + (size_t)mrow * 512 + k0 + lg * 8;
            f32x4 a0 = *(const f32x4*)ap;
            f32x4 a1 = *(const f32x4*)(ap + 4);
            #pragma unroll
            for (int j = 0; j < 4; ++j) {
                __bf16 h = (__bf16)a0[j]; ah[j] = h; al[j] = (__bf16)(a0[j] - (float)h);
            }
            #pragma unroll
            for (int j = 0; j < 4; ++j) {
                __bf16 h = (__bf16)a1[j]; ah[4 + j] = h; al[4 + j] = (__bf16)(a1[j] - (float)h);
            }
        } else {
            ah = *(const bf16x8*)(Ahi + (size_t)mrow * 512 + k0 + lg * 8);
            al = *(const bf16x8*)(Alo + (size_t)mrow * 512 + k0 + lg * 8);
        }
        #pragma unroll
        for (int nt = 0; nt < 4; ++nt) {
            bf16x8 bh = *(const bf16x8*)(wp + (size_t)nt * 16 * 512 + k0);
            bf16x8 bl = *(const bf16x8*)(wl + (size_t)nt * 16 * 512 + k0);
            acc[nt] = mfma16(ah, bh, acc[nt]);
            acc[nt] = mfma16(al, bh, acc[nt]);
            acc[nt] = mfma16(ah, bl, acc[nt]);
        }
    }

    #pragma unroll
    for (int nt = 0; nt < 4; ++nt) {
        int n = n0 + nt * 16 + l15;
        float bz = bias[n];
        #pragma unroll
        for (int rr = 0; rr < 4; ++rr) {
            int m = m0 + w * 16 + lg * 4 + rr;
            float v = acc[nt][rr] + bz;
            if (OM == 0) {
                Cf[(size_t)m * 512 + n] = v;
            } else {
                int b = m >> 10, s = m & 1023, h = n >> 6, d = n & 63;
                if (OM == 1)
                    Cb[((size_t)(b * HH + h) * SS + s) * 64 + d] = (__bf16)v;
                else
                    Cb[((size_t)(b * HH + h) * 64 + d) * SS + s] = (__bf16)v;
            }
        }
    }
}

// ---------------- Fused attention: fixed-shift softmax, wave-per-head ----------------
// grid flat 512: qt = id>>3, b = id&7 (XCD = b). 512 thr = 8 waves = 8 heads.
__global__ __launch_bounds__(512, 4) void attn2(
    const __bf16* __restrict__ qh, const __bf16* __restrict__ kh,
    const __bf16* __restrict__ vt,
    const float* __restrict__ mask, const float* __restrict__ adj,
    const float* __restrict__ dist,
    float* __restrict__ attn_out, __bf16* __restrict__ chi, __bf16* __restrict__ clo)
{
    __shared__ float nmb[1024];                    // (nm - 16) * log2e
    __shared__ __align__(16) __bf16 G[16][1028];   // adj * exp(dist+nm-1)
    __shared__ __align__(16) __bf16 Pch[8][16][40];
    __shared__ float rowIL[16];

    const int tid = threadIdx.x;
    const int w = tid >> 6, lane = tid & 63, l15 = lane & 15, lg = lane >> 4;
    const int q0 = (blockIdx.x >> 3) * 16;
    const int b = blockIdx.x & 7;
    const float L2E = 1.44269504f;

    #pragma unroll
    for (int i = 0; i < 2; ++i) {
        int c = tid + 512 * i;
        nmb[c] = fmaf(mask[(size_t)b * SS + c], -1e9f * L2E, -16.0f * L2E);
    }
    __syncthreads();

    // ---- G = adj * exp2(dist*L2E + (nm-1)*L2E); rowIL = 1/sum ----
    {
        const int row = 2 * w + (lg >> 1);
        const int kb = (lg & 1) * 512;
        const size_t drow = ((size_t)b * SS + q0 + row) * SS;
        float sm = 0.f;
        #pragma unroll
        for (int j = 0; j < 8; ++j) {
            int c = kb + l15 * 4 + j * 64;
            f32x4 d4 = *(const f32x4*)(dist + drow + c);
            f32x4 a4 = *(const f32x4*)(adj + drow + c);
            f32x4 n4 = *(const f32x4*)&nmb[c];
            bf16x4 g4;
            #pragma unroll
            for (int r = 0; r < 4; ++r) {
                float e = exp2f(fmaf(d4[r], L2E, n4[r] + 15.0f * L2E));
                sm += e;
                g4[r] = (__bf16)(a4[r] * e);
            }
            *(bf16x4*)&G[row][c] = g4;
        }
        #pragma unroll
        for (int off = 1; off <= 16; off <<= 1)
            sm += __shfl_xor(sm, off, 64);
        if ((lane & 31) == 0) rowIL[row] = 1.0f / sm;
    }
    __syncthreads();

    // ---- per-wave head = w ----
    const size_t hb = ((size_t)(b * HH + w)) * SS * 64;
    bf16x8 qf[2];
    #pragma unroll
    for (int ks = 0; ks < 2; ++ks)
        qf[ks] = *(const bf16x8*)(qh + hb + (size_t)(q0 + l15) * 64 + ks * 32 + lg * 8);
    const float c1 = 0.125f * L2E;
    const __bf16* kp = kh + hb + (size_t)l15 * 64 + lg * 8;

    // pass 1: l = sum exp2(s*L2E - 16*L2E)
    float l = 0.f;
    #pragma unroll 4
    for (int nt = 0; nt < 64; ++nt) {
        f32x4 acc = {0.f, 0.f, 0.f, 0.f};
        bf16x8 k0v = *(const bf16x8*)(kp + (size_t)nt * 1024);
        bf16x8 k1v = *(const bf16x8*)(kp + (size_t)nt * 1024 + 32);
        acc = mfma16(k0v, qf[0], acc);
        acc = mfma16(k1v, qf[1], acc);
        f32x4 nb4 = *(const f32x4*)&nmb[nt * 16 + lg * 4];
        float e0 = exp2f(fmaf(acc[0], c1, nb4[0]));
        float e1 = exp2f(fmaf(acc[1], c1, nb4[1]));
        float e2 = exp2f(fmaf(acc[2], c1, nb4[2]));
        float e3 = exp2f(fmaf(acc[3], c1, nb4[3]));
        l += (e0 + e1) + (e2 + e3);
    }
    #pragma unroll
    for (int off = 16; off <= 32; off <<= 1)
        l += __shfl_xor(l, off, 64);
    const float coef = (1.0f / l) * rowIL[l15];

    // pass 2: recompute S, gate, write attn, PV
    f32x4 cacc[4];
    #pragma unroll
    for (int dt = 0; dt < 4; ++dt) cacc[dt] = (f32x4){0.f, 0.f, 0.f, 0.f};
    float* aout = attn_out + ((size_t)(b * HH + w)) * SS * SS + (size_t)(q0 + l15) * SS;

    for (int c = 0; c < 32; ++c) {
        #pragma unroll
        for (int t = 0; t < 2; ++t) {
            int nt = c * 2 + t;
            f32x4 acc = {0.f, 0.f, 0.f, 0.f};
            bf16x8 k0v = *(const bf16x8*)(kp + (size_t)nt * 1024);
            bf16x8 k1v = *(const bf16x8*)(kp + (size_t)nt * 1024 + 32);
            acc = mfma16(k0v, qf[0], acc);
            acc = mfma16(k1v, qf[1], acc);
            f32x4 nb4 = *(const f32x4*)&nmb[nt * 16 + lg * 4];
            bf16x4 g4 = *(const bf16x4*)&G[l15][nt * 16 + lg * 4];
            f32x4 av; bf16x4 pb;
            #pragma unroll
            for (int r = 0; r < 4; ++r) {
                float e = exp2f(fmaf(acc[r], c1, nb4[r]));
                float x = e * coef * (float)g4[r];
                av[r] = x; pb[r] = (__bf16)x;
            }
            __builtin_nontemporal_store(av, (f32x4*)(aout + nt * 16 + lg * 4));
            *(bf16x4*)&Pch[w][l15][t * 16 + lg * 4] = pb;
        }
        bf16x8 pa = *(const bf16x8*)&Pch[w][l15][lg * 8];
        const __bf16* vb = vt + ((size_t)(b * HH + w) * 64 + l15) * SS + c * 32 + lg * 8;
        #pragma unroll
        for (int dt = 0; dt < 4; ++dt)
            cacc[dt] = mfma16(pa, *(const bf16x8*)(vb + (size_t)dt * 16 * SS), cacc[dt]);
    }

    // epilogue: ctx -> bf16 hi/lo in [m][512] layout
    #pragma unroll
    for (int dt = 0; dt < 4; ++dt)
        #pragma unroll
        for (int r = 0; r < 4; ++r) {
            float x = cacc[dt][r];
            __bf16 hv = (__bf16)x;
            size_t idx = ((size_t)b * SS + q0 + lg * 4 + r) * DM + w * 64 + dt * 16 + l15;
            chi[idx] = hv;
            clo[idx] = (__bf16)(x - (float)hv);
        }
}

extern "C" void kernel_launch(void* const* d_in, const int* in_sizes, int n_in,
                              void* d_out, int out_size, void* d_ws, size_t ws_size,
                              hipStream_t stream) {
    const float* q    = (const float*)d_in[0];
    const float* k    = (const float*)d_in[1];
    const float* v    = (const float*)d_in[2];
    const float* mask = (const float*)d_in[3];
    const float* adj  = (const float*)d_in[4];
    const float* dist = (const float*)d_in[5];
    const float* Wq   = (const float*)d_in[6];
    const float* bq   = (const float*)d_in[7];
    const float* Wk   = (const float*)d_in[8];
    const float* bk   = (const float*)d_in[9];
    const float* Wv   = (const float*)d_in[10];
    const float* bv   = (const float*)d_in[11];
    const float* Wo   = (const float*)d_in[12];
    const float* bo   = (const float*)d_in[13];

    const size_t NT = (size_t)BB * SS * DM;   // 4,194,304
    const size_t WN = 512 * 512;
    __bf16* wth = (__bf16*)d_ws;
    __bf16* wtl = wth + 4 * WN;
    __bf16* qhb = wtl + 4 * WN;
    __bf16* khb = qhb + NT;
    __bf16* vtb = khb + NT;
    __bf16* chi = vtb + NT;
    __bf16* clo = chi + NT;

    float* outp = (float*)d_out;
    float* attn = outp + NT;

    wconv<<<dim3(8, 8, 4), 256, 0, stream>>>(Wq, Wk, Wv, Wo, wth, wtl);

    dim3 gg(8, 128);
    gemm_mfma<0, 1><<<gg, 256, 0, stream>>>(q, nullptr, nullptr, wth, wtl, bq, nullptr, qhb);
    gemm_mfma<0, 1><<<gg, 256, 0, stream>>>(k, nullptr, nullptr, wth + WN, wtl + WN, bk, nullptr, khb);
    gemm_mfma<0, 2><<<gg, 256, 0, stream>>>(v, nullptr, nullptr, wth + 2 * WN, wtl + 2 * WN, bv, nullptr, vtb);

    attn2<<<512, 512, 0, stream>>>(qhb, khb, vtb, mask, adj, dist, attn, chi, clo);

    gemm_mfma<1, 0><<<gg, 256, 0, stream>>>(nullptr, chi, clo, wth + 3 * WN, wtl + 3 * WN, bo, outp, nullptr);
}